// Round 6
// baseline (721.964 us; speedup 1.0000x reference)
//
#include <hip/hip_runtime.h>
#include <hip/hip_bf16.h>
#include <math.h>

#define N_NODES 50000
#define M_PAD   50048           // 782 * 64 rows; fc0 uses 1564 * 32
#define E_EDGES 800000
#define IN_DIM  512
#define HDIM    128
#define CDIM    40
#define LAYERS  8
#define NB      196             // scan blocks: ceil(50000/256)

typedef __attribute__((ext_vector_type(8))) short short8;
typedef __attribute__((ext_vector_type(4))) float floatx4;
typedef unsigned short ushort_t;

__device__ inline float bf2f(unsigned short u) {
    return __uint_as_float(((unsigned)u) << 16);
}
__device__ inline unsigned short f2bf(float v) {
    __hip_bfloat16 b = __float2bfloat16(v);
    return *reinterpret_cast<unsigned short*>(&b);
}

// ---------------- CSR build ----------------

__global__ void hist_kernel(const int* __restrict__ dst, int* __restrict__ cnt) {
    int i = blockIdx.x * blockDim.x + threadIdx.x;
    if (i < E_EDGES) atomicAdd(&cnt[dst[i]], 1);
}

__global__ void scanA(const int* __restrict__ cnt, int* __restrict__ bsum) {
    __shared__ int sm[256];
    int t = threadIdx.x, i = blockIdx.x * 256 + t;
    sm[t] = (i < N_NODES) ? cnt[i] : 0;
    __syncthreads();
    for (int d = 128; d > 0; d >>= 1) {
        if (t < d) sm[t] += sm[t + d];
        __syncthreads();
    }
    if (t == 0) bsum[blockIdx.x] = sm[0];
}

__global__ void scanB(const int* __restrict__ bsum, int* __restrict__ boff) {
    __shared__ int sm[256];
    int t = threadIdx.x;
    sm[t] = (t < NB) ? bsum[t] : 0;
    __syncthreads();
    for (int d = 1; d < 256; d <<= 1) {
        int v = (t >= d) ? sm[t - d] : 0;
        __syncthreads();
        sm[t] += v;
        __syncthreads();
    }
    if (t < NB) boff[t] = (t > 0) ? sm[t - 1] : 0;
}

__global__ void scanC(const int* __restrict__ cnt, const int* __restrict__ boff,
                      int* __restrict__ row_start, int* __restrict__ cursor) {
    __shared__ int sm[256];
    int t = threadIdx.x, i = blockIdx.x * 256 + t;
    int v = (i < N_NODES) ? cnt[i] : 0;
    sm[t] = v;
    __syncthreads();
    for (int d = 1; d < 256; d <<= 1) {
        int x = (t >= d) ? sm[t - d] : 0;
        __syncthreads();
        sm[t] += x;
        __syncthreads();
    }
    if (i < N_NODES) {
        int incl = boff[blockIdx.x] + sm[t];
        int excl = incl - v;
        row_start[i] = excl;
        cursor[i]    = excl;
        if (i == N_NODES - 1) row_start[N_NODES] = incl;
    }
}

__global__ void scatter_kernel(const int* __restrict__ ei, const float* __restrict__ normA,
                               int* __restrict__ cursor, int2* __restrict__ perm) {
    int i = blockIdx.x * blockDim.x + threadIdx.x;
    if (i >= E_EDGES) return;
    int d = ei[E_EDGES + i];
    int idx = atomicAdd(&cursor[d], 1);
    perm[idx] = make_int2(ei[i], __float_as_int(normA[i]));
}

// ---------------- weight prep: transpose + bf16 convert ----------------

__global__ void prep_weights(const float* __restrict__ W0, const float* __restrict__ convW,
                             const float* __restrict__ W1,
                             ushort_t* __restrict__ Wt0, ushort_t* __restrict__ WtL,
                             ushort_t* __restrict__ Wt1) {
    int i = blockIdx.x * blockDim.x + threadIdx.x;
    if (i < 128 * 512) {
        int n = i >> 9, k = i & 511;
        Wt0[i] = f2bf(W0[k * HDIM + n]);
        return;
    }
    int j = i - 128 * 512;
    if (j < 8 * 128 * 128) {
        int l = j >> 14, rem = j & 16383, n = rem >> 7, k = rem & 127;
        WtL[j] = f2bf(convW[l * 16384 + k * HDIM + n]);
        return;
    }
    int m = j - 8 * 128 * 128;
    if (m < 48 * 128) {
        int n = m >> 7, k = m & 127;
        Wt1[m] = (n < CDIM) ? f2bf(W1[k * CDIM + n]) : (ushort_t)0;
    }
}

// ---------------- fc0: x = relu(F @ W0 + b0) -> h0b (bf16) ----------------
// Block = 128 thr = 2 waves sharing one 32-row tile; each wave owns 64 cols
// (cg = wave). B-amortization stays 0.5 loads/MFMA; A is read by both waves
// but the second read hits L1/L2 (co-resident). Grid = 1564 -> 3 waves/SIMD.

__global__ __launch_bounds__(128)
void fc0_mfma(const float* __restrict__ F, const ushort_t* __restrict__ Wt0,
              const float* __restrict__ b0, ushort_t* __restrict__ h0b) {
    int t = threadIdx.x;
    int cg = t >> 6, lane = t & 63;
    int quad = lane >> 4, l16 = lane & 15;
    int R0 = blockIdx.x * 32;

    int r0 = R0 + l16;      if (r0 > N_NODES - 1) r0 = N_NODES - 1;
    int r1 = R0 + 16 + l16; if (r1 > N_NODES - 1) r1 = N_NODES - 1;
    const float* ap0 = F + (size_t)r0 * IN_DIM + quad * 8;
    const float* ap1 = F + (size_t)r1 * IN_DIM + quad * 8;
    const ushort_t* bbase = Wt0 + (size_t)(cg * 64 + l16) * IN_DIM + quad * 8;

    floatx4 acc0[4], acc1[4];
#pragma unroll
    for (int nt = 0; nt < 4; nt++) {
        acc0[nt] = (floatx4){0.f, 0.f, 0.f, 0.f};
        acc1[nt] = (floatx4){0.f, 0.f, 0.f, 0.f};
    }

    // 4-deep prefetch ring
    float4 pf[4][4];
#pragma unroll
    for (int d = 0; d < 4; d++) {
        pf[d][0] = *(const float4*)(ap0 + d * 32);
        pf[d][1] = *(const float4*)(ap0 + d * 32 + 4);
        pf[d][2] = *(const float4*)(ap1 + d * 32);
        pf[d][3] = *(const float4*)(ap1 + d * 32 + 4);
    }

#pragma unroll
    for (int ks = 0; ks < 16; ks++) {
        float4 lo0 = pf[ks & 3][0], hi0 = pf[ks & 3][1];
        float4 lo1 = pf[ks & 3][2], hi1 = pf[ks & 3][3];
        short8 a0, a1;
        a0[0] = (short)f2bf(lo0.x); a0[1] = (short)f2bf(lo0.y);
        a0[2] = (short)f2bf(lo0.z); a0[3] = (short)f2bf(lo0.w);
        a0[4] = (short)f2bf(hi0.x); a0[5] = (short)f2bf(hi0.y);
        a0[6] = (short)f2bf(hi0.z); a0[7] = (short)f2bf(hi0.w);
        a1[0] = (short)f2bf(lo1.x); a1[1] = (short)f2bf(lo1.y);
        a1[2] = (short)f2bf(lo1.z); a1[3] = (short)f2bf(lo1.w);
        a1[4] = (short)f2bf(hi1.x); a1[5] = (short)f2bf(hi1.y);
        a1[6] = (short)f2bf(hi1.z); a1[7] = (short)f2bf(hi1.w);
        if (ks + 4 < 16) {
            pf[ks & 3][0] = *(const float4*)(ap0 + (ks + 4) * 32);
            pf[ks & 3][1] = *(const float4*)(ap0 + (ks + 4) * 32 + 4);
            pf[ks & 3][2] = *(const float4*)(ap1 + (ks + 4) * 32);
            pf[ks & 3][3] = *(const float4*)(ap1 + (ks + 4) * 32 + 4);
        }
#pragma unroll
        for (int nt = 0; nt < 4; nt++) {
            short8 b = *(const short8*)(bbase + (size_t)nt * 16 * IN_DIM + ks * 32);
            acc0[nt] = __builtin_amdgcn_mfma_f32_16x16x32_bf16(a0, b, acc0[nt], 0, 0, 0);
            acc1[nt] = __builtin_amdgcn_mfma_f32_16x16x32_bf16(a1, b, acc1[nt], 0, 0, 0);
        }
    }

#pragma unroll
    for (int nt = 0; nt < 4; nt++) {
        int col = cg * 64 + nt * 16 + l16;
        float bias = b0[col];
#pragma unroll
        for (int r = 0; r < 4; r++) {
            int row = R0 + quad * 4 + r;
            float v = acc0[nt][r] + bias;
            v = v > 0.f ? v : 0.f;
            h0b[(size_t)row * HDIM + col] = f2bf(v);
        }
#pragma unroll
        for (int r = 0; r < 4; r++) {
            int row = R0 + 16 + quad * 4 + r;
            float v = acc1[nt][r] + bias;
            v = v > 0.f ? v : 0.f;
            h0b[(size_t)row * HDIM + col] = f2bf(v);
        }
    }
}

// -------- fused layer: sup = 0.9*(A x)+0.1*h0 (into LDS); x' = relu(beta*(sup W)+(1-beta)*sup)
// block = 64 rows, 512 thr / 8 waves. spmm: 32 groups of 16 lanes -> only
// 2 rows SERIAL per group (halves exposed gather latency vs 4), plus ~20
// waves/CU. Per-row acc dies into LDS (no spill; round-4 lesson). Next-row
// perm prefetch hides the perm L2 round-trip.
// gemm: wave w = (row-tile w>>1, col-half w&1): 16 rows x 64 cols each.

#define SROW 136   // 128 + 8 pad

__device__ __forceinline__ void spmm_proc16(int2 pm, const ushort_t* __restrict__ xb,
                                            int sl, float* __restrict__ acc) {
#pragma unroll
    for (int j = 0; j < 16; j += 4) {
        int   s0 = __shfl(pm.x, j + 0, 16);
        int   s1 = __shfl(pm.x, j + 1, 16);
        int   s2 = __shfl(pm.x, j + 2, 16);
        int   s3 = __shfl(pm.x, j + 3, 16);
        float w0 = __int_as_float(__shfl(pm.y, j + 0, 16));
        float w1 = __int_as_float(__shfl(pm.y, j + 1, 16));
        float w2 = __int_as_float(__shfl(pm.y, j + 2, 16));
        float w3 = __int_as_float(__shfl(pm.y, j + 3, 16));
        short8 v0 = *(const short8*)(xb + (size_t)s0 * HDIM + sl * 8);
        short8 v1 = *(const short8*)(xb + (size_t)s1 * HDIM + sl * 8);
        short8 v2 = *(const short8*)(xb + (size_t)s2 * HDIM + sl * 8);
        short8 v3 = *(const short8*)(xb + (size_t)s3 * HDIM + sl * 8);
#pragma unroll
        for (int c = 0; c < 8; c++) {
            acc[c] += w0 * bf2f((ushort_t)v0[c]);
            acc[c] += w1 * bf2f((ushort_t)v1[c]);
            acc[c] += w2 * bf2f((ushort_t)v2[c]);
            acc[c] += w3 * bf2f((ushort_t)v3[c]);
        }
    }
}

__global__ __launch_bounds__(512)
void layer_fused(const int* __restrict__ row_start, const int2* __restrict__ perm,
                 const ushort_t* __restrict__ xb, const ushort_t* __restrict__ h0b,
                 const ushort_t* __restrict__ Wt, ushort_t* __restrict__ X,
                 float beta) {
    __shared__ short sS[64][SROW];   // 17.4 KB
    int t = threadIdx.x;
    int wave = t >> 6, lane = t & 63;
    int grp = lane >> 4, sl = lane & 15;
    int quad = lane >> 4, l16 = lane & 15;   // gemm aliases
    int row0 = blockIdx.x * 64;
    int G = wave * 4 + grp;                  // block-local group 0..31
    int Rg = row0 + G * 2;                   // 2 rows per group

    // row bounds for this group's 2 rows
    int rbv = 0;
    if (sl <= 2) {
        int idx = Rg + sl; if (idx > N_NODES) idx = N_NODES;
        rbv = row_start[idx];
    }
    int e0[2], e1[2];
#pragma unroll
    for (int r = 0; r < 2; r++) {
        e0[r] = __shfl(rbv, r, 16);
        e1[r] = __shfl(rbv, r + 1, 16);
    }

    // prefetch row 0's chunk-0 perm entries
    int2 pA = make_int2(0, 0), pB = make_int2(0, 0);
    if (e0[0] + sl < e1[0])      pA = perm[e0[0] + sl];
    if (e0[0] + 16 + sl < e1[0]) pB = perm[e0[0] + 16 + sl];

#pragma unroll
    for (int r = 0; r < 2; r++) {
        // prefetch next row's perm before touching this row's gathers
        int2 nA = make_int2(0, 0), nB = make_int2(0, 0);
        if (r < 1) {
            if (e0[r + 1] + sl < e1[r + 1])      nA = perm[e0[r + 1] + sl];
            if (e0[r + 1] + 16 + sl < e1[r + 1]) nB = perm[e0[r + 1] + 16 + sl];
        }

        float acc[8];
#pragma unroll
        for (int c = 0; c < 8; c++) acc[c] = 0.f;

        spmm_proc16(pA, xb, sl, acc);
        spmm_proc16(pB, xb, sl, acc);

        // rare tails (degree > 32)
        for (int chunk = e0[r] + 32; chunk < e1[r]; chunk += 32) {
            int2 qa = make_int2(0, 0), qb = make_int2(0, 0);
            if (chunk + sl < e1[r])      qa = perm[chunk + sl];
            if (chunk + 16 + sl < e1[r]) qb = perm[chunk + 16 + sl];
            spmm_proc16(qa, xb, sl, acc);
            spmm_proc16(qb, xb, sl, acc);
        }

        // blend with h0 and stage to LDS (acc dies here)
        int row = Rg + r;
        short8 o;
        if (row < N_NODES) {
            short8 h = *(const short8*)(h0b + (size_t)row * HDIM + sl * 8);
#pragma unroll
            for (int c = 0; c < 8; c++)
                o[c] = (short)f2bf(0.9f * acc[c] + 0.1f * bf2f((ushort_t)h[c]));
        } else {
#pragma unroll
            for (int c = 0; c < 8; c++) o[c] = 0;
        }
        *(short8*)&sS[G * 2 + r][sl * 8] = o;

        pA = nA; pB = nB;
    }
    __syncthreads();

    // ---- gemm phase: wave w -> row-tile (w>>1), col-half (w&1) ----
    int rw = wave >> 1, ch = wave & 1;
    short8 afrag[4];
#pragma unroll
    for (int ks = 0; ks < 4; ks++)
        afrag[ks] = *(const short8*)&sS[rw * 16 + l16][ks * 32 + quad * 8];

    floatx4 gacc[4];
#pragma unroll
    for (int nt = 0; nt < 4; nt++) {
        const ushort_t* bp = Wt + (size_t)(ch * 64 + nt * 16 + l16) * HDIM + quad * 8;
        floatx4 c = (floatx4){0.f, 0.f, 0.f, 0.f};
#pragma unroll
        for (int ks = 0; ks < 4; ks++) {
            short8 b = *(const short8*)(bp + ks * 32);
            c = __builtin_amdgcn_mfma_f32_16x16x32_bf16(afrag[ks], b, c, 0, 0, 0);
        }
        gacc[nt] = c;
    }
    float g = 1.f - beta;
#pragma unroll
    for (int nt = 0; nt < 4; nt++) {
        int col = ch * 64 + nt * 16 + l16;
#pragma unroll
        for (int r = 0; r < 4; r++) {
            int lrow = rw * 16 + quad * 4 + r;
            float s = bf2f((ushort_t)sS[lrow][col]);
            float v = beta * gacc[nt][r] + g * s;
            v = v > 0.f ? v : 0.f;
            X[(size_t)(row0 + lrow) * HDIM + col] = f2bf(v);
        }
    }
}

// ---------------- fc1: out = x @ W1 + b1 (fp32 out), N padded 40->48 ----------------

__global__ void fc1_mfma(const ushort_t* __restrict__ X, const ushort_t* __restrict__ Wt1,
                         const float* __restrict__ b1, float* __restrict__ out) {
    int wave = threadIdx.x >> 6;
    int lane = threadIdx.x & 63;
    int quad = lane >> 4, l16 = lane & 15;
    int row0 = blockIdx.x * 64 + wave * 16;

    int arow = row0 + l16; if (arow > N_NODES - 1) arow = N_NODES - 1;
    const ushort_t* ap = X + (size_t)arow * HDIM + quad * 8;
    short8 afrag[4];
#pragma unroll
    for (int ks = 0; ks < 4; ks++) afrag[ks] = *(const short8*)(ap + ks * 32);

    floatx4 acc[3];
#pragma unroll
    for (int nt = 0; nt < 3; nt++) {
        const ushort_t* bp = Wt1 + (size_t)(nt * 16 + l16) * HDIM + quad * 8;
        floatx4 c = (floatx4){0.f, 0.f, 0.f, 0.f};
#pragma unroll
        for (int ks = 0; ks < 4; ks++) {
            short8 b = *(const short8*)(bp + ks * 32);
            c = __builtin_amdgcn_mfma_f32_16x16x32_bf16(afrag[ks], b, c, 0, 0, 0);
        }
        acc[nt] = c;
    }
#pragma unroll
    for (int nt = 0; nt < 3; nt++) {
        int col = nt * 16 + l16;
        if (col < CDIM) {
            float bias = b1[col];
#pragma unroll
            for (int r = 0; r < 4; r++) {
                int row = row0 + quad * 4 + r;
                if (row < N_NODES)
                    out[(size_t)row * CDIM + col] = acc[nt][r] + bias;
            }
        }
    }
}

// ---------------- launch ----------------

extern "C" void kernel_launch(void* const* d_in, const int* in_sizes, int n_in,
                              void* d_out, int out_size, void* d_ws, size_t ws_size,
                              hipStream_t stream) {
    const float* F     = (const float*)d_in[0];
    const int*   ei    = (const int*)d_in[1];
    const float* normA = (const float*)d_in[2];
    const float* W0    = (const float*)d_in[3];
    const float* b0    = (const float*)d_in[4];
    const float* convW = (const float*)d_in[5];
    const float* W1    = (const float*)d_in[6];
    const float* b1    = (const float*)d_in[7];
    float*       out   = (float*)d_out;

    // workspace layout (bf16 trunk), 16B-aligned
    ushort_t* h0b  = (ushort_t*)d_ws;                     // M_PAD*128
    ushort_t* xab  = h0b + (size_t)M_PAD * HDIM;
    ushort_t* xbb  = xab + (size_t)M_PAD * HDIM;
    ushort_t* Wt0  = xbb + (size_t)M_PAD * HDIM;          // 128*512
    ushort_t* WtL  = Wt0 + 128 * 512;                     // 8*128*128
    ushort_t* Wt1  = WtL + 8 * 128 * 128;                 // 48*128
    int*   row_start = (int*)(Wt1 + 48 * 128);
    int*   cursor    = row_start + (N_NODES + 8);
    int*   cnt       = cursor + (N_NODES + 8);
    int*   bsum      = cnt + (N_NODES + 8);
    int*   boff      = bsum + 256;
    int2*  perm      = (int2*)(boff + 256);               // 8B-aligned

    // CSR build
    hipMemsetAsync(cnt, 0, N_NODES * sizeof(int), stream);
    hist_kernel<<<(E_EDGES + 255) / 256, 256, 0, stream>>>(ei + E_EDGES, cnt);
    scanA<<<NB, 256, 0, stream>>>(cnt, bsum);
    scanB<<<1, 256, 0, stream>>>(bsum, boff);
    scanC<<<NB, 256, 0, stream>>>(cnt, boff, row_start, cursor);
    scatter_kernel<<<(E_EDGES + 255) / 256, 256, 0, stream>>>(ei, normA, cursor, perm);
    prep_weights<<<(128 * 512 + 8 * 128 * 128 + 48 * 128 + 255) / 256, 256, 0, stream>>>(
        W0, convW, W1, Wt0, WtL, Wt1);

    fc0_mfma<<<M_PAD / 32, 128, 0, stream>>>(F, Wt0, b0, h0b);

    // after fc0, x == h0: layer 0 reads h0b as both x and h0
    ushort_t* ping = h0b;
    ushort_t* pong = xab;
    for (int i = 0; i < LAYERS; i++) {
        float beta = logf(0.5f / (float)(i + 1) + 1.0f);
        layer_fused<<<M_PAD / 64, 512, 0, stream>>>(
            row_start, perm, ping, h0b, WtL + (size_t)i * HDIM * HDIM, pong, beta);
        if (i == 0) { ping = xab; pong = xbb; }
        else { ushort_t* tmp = ping; ping = pong; pong = tmp; }
    }
    // L0->xab, L1->xbb, ..., L7->xbb; ping == xbb here
    fc1_mfma<<<M_PAD / 64, 256, 0, stream>>>(ping, Wt1, b1, out);
}

// Round 7
// 683.574 us; speedup vs baseline: 1.0562x; 1.0562x over previous
//
#include <hip/hip_runtime.h>
#include <hip/hip_bf16.h>
#include <math.h>

#define N_NODES 50000
#define M_PAD   50048           // 782 * 64 rows; fc0 uses 1564 * 32
#define E_EDGES 800000
#define IN_DIM  512
#define HDIM    128
#define CDIM    40
#define LAYERS  8
#define NB      196             // scan blocks: ceil(50000/256)

typedef __attribute__((ext_vector_type(8))) short short8;
typedef __attribute__((ext_vector_type(4))) float floatx4;
typedef unsigned short ushort_t;

__device__ inline float bf2f(unsigned short u) {
    return __uint_as_float(((unsigned)u) << 16);
}
__device__ inline unsigned short f2bf(float v) {
    __hip_bfloat16 b = __float2bfloat16(v);
    return *reinterpret_cast<unsigned short*>(&b);
}

// ---------------- CSR build ----------------

__global__ void hist_kernel(const int* __restrict__ dst, int* __restrict__ cnt) {
    int i = blockIdx.x * blockDim.x + threadIdx.x;
    if (i < E_EDGES) atomicAdd(&cnt[dst[i]], 1);
}

__global__ void scanA(const int* __restrict__ cnt, int* __restrict__ bsum) {
    __shared__ int sm[256];
    int t = threadIdx.x, i = blockIdx.x * 256 + t;
    sm[t] = (i < N_NODES) ? cnt[i] : 0;
    __syncthreads();
    for (int d = 128; d > 0; d >>= 1) {
        if (t < d) sm[t] += sm[t + d];
        __syncthreads();
    }
    if (t == 0) bsum[blockIdx.x] = sm[0];
}

__global__ void scanB(const int* __restrict__ bsum, int* __restrict__ boff) {
    __shared__ int sm[256];
    int t = threadIdx.x;
    sm[t] = (t < NB) ? bsum[t] : 0;
    __syncthreads();
    for (int d = 1; d < 256; d <<= 1) {
        int v = (t >= d) ? sm[t - d] : 0;
        __syncthreads();
        sm[t] += v;
        __syncthreads();
    }
    if (t < NB) boff[t] = (t > 0) ? sm[t - 1] : 0;
}

__global__ void scanC(const int* __restrict__ cnt, const int* __restrict__ boff,
                      int* __restrict__ row_start, int* __restrict__ cursor) {
    __shared__ int sm[256];
    int t = threadIdx.x, i = blockIdx.x * 256 + t;
    int v = (i < N_NODES) ? cnt[i] : 0;
    sm[t] = v;
    __syncthreads();
    for (int d = 1; d < 256; d <<= 1) {
        int x = (t >= d) ? sm[t - d] : 0;
        __syncthreads();
        sm[t] += x;
        __syncthreads();
    }
    if (i < N_NODES) {
        int incl = boff[blockIdx.x] + sm[t];
        int excl = incl - v;
        row_start[i] = excl;
        cursor[i]    = excl;
        if (i == N_NODES - 1) row_start[N_NODES] = incl;
    }
}

__global__ void scatter_kernel(const int* __restrict__ ei, const float* __restrict__ normA,
                               int* __restrict__ cursor, int2* __restrict__ perm) {
    int i = blockIdx.x * blockDim.x + threadIdx.x;
    if (i >= E_EDGES) return;
    int d = ei[E_EDGES + i];
    int idx = atomicAdd(&cursor[d], 1);
    perm[idx] = make_int2(ei[i], __float_as_int(normA[i]));
}

// ---------------- weight prep: transpose + bf16 convert ----------------

__global__ void prep_weights(const float* __restrict__ W0, const float* __restrict__ convW,
                             const float* __restrict__ W1,
                             ushort_t* __restrict__ Wt0, ushort_t* __restrict__ WtL,
                             ushort_t* __restrict__ Wt1) {
    int i = blockIdx.x * blockDim.x + threadIdx.x;
    if (i < 128 * 512) {
        int n = i >> 9, k = i & 511;
        Wt0[i] = f2bf(W0[k * HDIM + n]);
        return;
    }
    int j = i - 128 * 512;
    if (j < 8 * 128 * 128) {
        int l = j >> 14, rem = j & 16383, n = rem >> 7, k = rem & 127;
        WtL[j] = f2bf(convW[l * 16384 + k * HDIM + n]);
        return;
    }
    int m = j - 8 * 128 * 128;
    if (m < 48 * 128) {
        int n = m >> 7, k = m & 127;
        Wt1[m] = (n < CDIM) ? f2bf(W1[k * CDIM + n]) : (ushort_t)0;
    }
}

// ---------------- fc0: x = relu(F @ W0 + b0) -> h0b (bf16) ----------------
// Block = 256 thr / 4 waves sharing one 32-row A tile. A is staged fp32 into
// LDS via __builtin_amdgcn_global_load_lds (async DMA; the compiler cannot
// sink it -- rounds 3-6 showed register-ring prefetch gets collapsed).
// 4 chunks of 32x128 fp32 (16KB), double-buffered: barrier drains chunk c,
// then chunk c+1 is issued and flies during compute of chunk c.
// LDS bank fix (rule #21): linear gll dest + XOR-swizzled global SOURCE +
// the same XOR on the ds_read side: byte ^= (row&7)<<4  ->  2-way (free).
// Wave w owns cols w*32..w*32+31 (2 nt): B-amortization 0.5 loads/MFMA.

__global__ __launch_bounds__(256)
void fc0_mfma(const float* __restrict__ F, const ushort_t* __restrict__ Wt0,
              const float* __restrict__ b0, ushort_t* __restrict__ h0b) {
    __shared__ float sA[2][32 * 128];   // 2 x 16KB
    int t = threadIdx.x;
    int wave = t >> 6, lane = t & 63;
    int quad = lane >> 4, l16 = lane & 15;
    int R0 = blockIdx.x * 32;

    const ushort_t* bbase = Wt0 + (size_t)(wave * 32 + l16) * IN_DIM + quad * 8;

    floatx4 acc[2][2];   // [rowfrag][nt]
#pragma unroll
    for (int rf = 0; rf < 2; rf++)
#pragma unroll
        for (int nt = 0; nt < 2; nt++) acc[rf][nt] = (floatx4){0.f, 0.f, 0.f, 0.f};

    // ---- staging: 4 x 16B global_load_lds per thread per chunk ----
    // LDS cell byte X (linear) holds element (row = X>>9, colbyte = (X&511) ^ ((row&7)<<4))
    auto stage = [&](int cc, int buf) {
#pragma unroll
        for (int i = 0; i < 4; i++) {
            int X = i * 4096 + wave * 1024 + lane * 16;     // byte in 16KB chunk
            int row = X >> 9;
            int colb = (X & 511) ^ ((row & 7) << 4);
            int gr = R0 + row; if (gr > N_NODES - 1) gr = N_NODES - 1;
            const float* src = F + (size_t)gr * IN_DIM + cc * 128 + (colb >> 2);
            __builtin_amdgcn_global_load_lds(
                (const __attribute__((address_space(1))) unsigned int*)src,
                (__attribute__((address_space(3))) unsigned int*)&sA[buf][i * 1024 + wave * 256],
                16, 0, 0);
        }
    };

    stage(0, 0);

    int mask = (l16 & 7) << 4;                 // per-lane read swizzle (bytes)
    int ib0 = ((quad << 5) ^ mask) >> 2;       // float offsets within ks-block
    int ib1 = (((quad << 5) | 16) ^ mask) >> 2;

#pragma unroll
    for (int cc = 0; cc < 4; cc++) {
        __syncthreads();                       // drains vmcnt -> chunk cc in LDS
        if (cc < 3) stage(cc + 1, (cc + 1) & 1);
        const float* bufp = &sA[cc & 1][0];
        const float* r0p = bufp + l16 * 128;
        const float* r1p = bufp + (l16 + 16) * 128;
#pragma unroll
        for (int k2 = 0; k2 < 4; k2++) {
            int ks = cc * 4 + k2;
            float4 f00 = *(const float4*)(r0p + k2 * 32 + ib0);
            float4 f01 = *(const float4*)(r0p + k2 * 32 + ib1);
            float4 f10 = *(const float4*)(r1p + k2 * 32 + ib0);
            float4 f11 = *(const float4*)(r1p + k2 * 32 + ib1);
            short8 a0, a1;
            a0[0] = (short)f2bf(f00.x); a0[1] = (short)f2bf(f00.y);
            a0[2] = (short)f2bf(f00.z); a0[3] = (short)f2bf(f00.w);
            a0[4] = (short)f2bf(f01.x); a0[5] = (short)f2bf(f01.y);
            a0[6] = (short)f2bf(f01.z); a0[7] = (short)f2bf(f01.w);
            a1[0] = (short)f2bf(f10.x); a1[1] = (short)f2bf(f10.y);
            a1[2] = (short)f2bf(f10.z); a1[3] = (short)f2bf(f10.w);
            a1[4] = (short)f2bf(f11.x); a1[5] = (short)f2bf(f11.y);
            a1[6] = (short)f2bf(f11.z); a1[7] = (short)f2bf(f11.w);
#pragma unroll
            for (int nt = 0; nt < 2; nt++) {
                short8 b = *(const short8*)(bbase + (size_t)nt * 16 * IN_DIM + ks * 32);
                acc[0][nt] = __builtin_amdgcn_mfma_f32_16x16x32_bf16(a0, b, acc[0][nt], 0, 0, 0);
                acc[1][nt] = __builtin_amdgcn_mfma_f32_16x16x32_bf16(a1, b, acc[1][nt], 0, 0, 0);
            }
        }
    }

#pragma unroll
    for (int nt = 0; nt < 2; nt++) {
        int col = wave * 32 + nt * 16 + l16;
        float bias = b0[col];
#pragma unroll
        for (int r = 0; r < 4; r++) {
            int row = R0 + quad * 4 + r;
            float v = acc[0][nt][r] + bias;
            v = v > 0.f ? v : 0.f;
            h0b[(size_t)row * HDIM + col] = f2bf(v);
        }
#pragma unroll
        for (int r = 0; r < 4; r++) {
            int row = R0 + 16 + quad * 4 + r;
            float v = acc[1][nt][r] + bias;
            v = v > 0.f ? v : 0.f;
            h0b[(size_t)row * HDIM + col] = f2bf(v);
        }
    }
}

// -------- fused layer: sup = 0.9*(A x)+0.1*h0 (into LDS); x' = relu(beta*(sup W)+(1-beta)*sup)
// Round-5 structure (measured best): block = 64 rows, 256 thr / 4 waves; each
// 16-lane group owns 4 rows SERIALLY (per-row acc dies into LDS -> no spills),
// chunk-32 per row, next-row perm prefetch.

#define SROW 136   // 128 + 8 pad

__device__ __forceinline__ void spmm_proc16(int2 pm, const ushort_t* __restrict__ xb,
                                            int sl, float* __restrict__ acc) {
#pragma unroll
    for (int j = 0; j < 16; j += 4) {
        int   s0 = __shfl(pm.x, j + 0, 16);
        int   s1 = __shfl(pm.x, j + 1, 16);
        int   s2 = __shfl(pm.x, j + 2, 16);
        int   s3 = __shfl(pm.x, j + 3, 16);
        float w0 = __int_as_float(__shfl(pm.y, j + 0, 16));
        float w1 = __int_as_float(__shfl(pm.y, j + 1, 16));
        float w2 = __int_as_float(__shfl(pm.y, j + 2, 16));
        float w3 = __int_as_float(__shfl(pm.y, j + 3, 16));
        short8 v0 = *(const short8*)(xb + (size_t)s0 * HDIM + sl * 8);
        short8 v1 = *(const short8*)(xb + (size_t)s1 * HDIM + sl * 8);
        short8 v2 = *(const short8*)(xb + (size_t)s2 * HDIM + sl * 8);
        short8 v3 = *(const short8*)(xb + (size_t)s3 * HDIM + sl * 8);
#pragma unroll
        for (int c = 0; c < 8; c++) {
            acc[c] += w0 * bf2f((ushort_t)v0[c]);
            acc[c] += w1 * bf2f((ushort_t)v1[c]);
            acc[c] += w2 * bf2f((ushort_t)v2[c]);
            acc[c] += w3 * bf2f((ushort_t)v3[c]);
        }
    }
}

__global__ __launch_bounds__(256)
void layer_fused(const int* __restrict__ row_start, const int2* __restrict__ perm,
                 const ushort_t* __restrict__ xb, const ushort_t* __restrict__ h0b,
                 const ushort_t* __restrict__ Wt, ushort_t* __restrict__ X,
                 float beta) {
    __shared__ short sS[64][SROW];   // 17.4 KB
    int t = threadIdx.x;
    int wave = t >> 6, lane = t & 63;
    int grp = lane >> 4, sl = lane & 15;
    int quad = lane >> 4, l16 = lane & 15;   // gemm aliases
    int row0 = blockIdx.x * 64;
    int G = wave * 4 + grp;                  // block-local group 0..15
    int Rg = row0 + G * 4;                   // 4 rows per group

    // row bounds for this group's 4 rows: one lane-parallel load + shfl
    int rbv = 0;
    if (sl <= 4) {
        int idx = Rg + sl; if (idx > N_NODES) idx = N_NODES;
        rbv = row_start[idx];
    }
    int e0[4], e1[4];
#pragma unroll
    for (int r = 0; r < 4; r++) {
        e0[r] = __shfl(rbv, r, 16);
        e1[r] = __shfl(rbv, r + 1, 16);
    }

    // prefetch row 0's chunk-0 perm entries
    int2 pA = make_int2(0, 0), pB = make_int2(0, 0);
    if (e0[0] + sl < e1[0])      pA = perm[e0[0] + sl];
    if (e0[0] + 16 + sl < e1[0]) pB = perm[e0[0] + 16 + sl];

#pragma unroll
    for (int r = 0; r < 4; r++) {
        // prefetch next row's perm before touching this row's gathers
        int2 nA = make_int2(0, 0), nB = make_int2(0, 0);
        if (r < 3) {
            if (e0[r + 1] + sl < e1[r + 1])      nA = perm[e0[r + 1] + sl];
            if (e0[r + 1] + 16 + sl < e1[r + 1]) nB = perm[e0[r + 1] + 16 + sl];
        }

        float acc[8];
#pragma unroll
        for (int c = 0; c < 8; c++) acc[c] = 0.f;

        spmm_proc16(pA, xb, sl, acc);
        spmm_proc16(pB, xb, sl, acc);

        // rare tails (degree > 32)
        for (int chunk = e0[r] + 32; chunk < e1[r]; chunk += 32) {
            int2 qa = make_int2(0, 0), qb = make_int2(0, 0);
            if (chunk + sl < e1[r])      qa = perm[chunk + sl];
            if (chunk + 16 + sl < e1[r]) qb = perm[chunk + 16 + sl];
            spmm_proc16(qa, xb, sl, acc);
            spmm_proc16(qb, xb, sl, acc);
        }

        // blend with h0 and stage to LDS (acc dies here)
        int row = Rg + r;
        short8 o;
        if (row < N_NODES) {
            short8 h = *(const short8*)(h0b + (size_t)row * HDIM + sl * 8);
#pragma unroll
            for (int c = 0; c < 8; c++)
                o[c] = (short)f2bf(0.9f * acc[c] + 0.1f * bf2f((ushort_t)h[c]));
        } else {
#pragma unroll
            for (int c = 0; c < 8; c++) o[c] = 0;
        }
        *(short8*)&sS[G * 4 + r][sl * 8] = o;

        pA = nA; pB = nB;
    }
    __syncthreads();

    // ---- gemm phase ----
    short8 afrag[4];
#pragma unroll
    for (int ks = 0; ks < 4; ks++)
        afrag[ks] = *(const short8*)&sS[wave * 16 + l16][ks * 32 + quad * 8];

    floatx4 gacc[8];
#pragma unroll
    for (int nt = 0; nt < 8; nt++) {
        const ushort_t* bp = Wt + (size_t)(nt * 16 + l16) * HDIM + quad * 8;
        floatx4 c = (floatx4){0.f, 0.f, 0.f, 0.f};
#pragma unroll
        for (int ks = 0; ks < 4; ks++) {
            short8 b = *(const short8*)(bp + ks * 32);
            c = __builtin_amdgcn_mfma_f32_16x16x32_bf16(afrag[ks], b, c, 0, 0, 0);
        }
        gacc[nt] = c;
    }
    float g = 1.f - beta;
#pragma unroll
    for (int nt = 0; nt < 8; nt++) {
        int col = nt * 16 + l16;
#pragma unroll
        for (int r = 0; r < 4; r++) {
            int lrow = wave * 16 + quad * 4 + r;
            float s = bf2f((ushort_t)sS[lrow][col]);
            float v = beta * gacc[nt][r] + g * s;
            v = v > 0.f ? v : 0.f;
            X[(size_t)(row0 + lrow) * HDIM + col] = f2bf(v);
        }
    }
}

// ---------------- fc1: out = x @ W1 + b1 (fp32 out), N padded 40->48 ----------------

__global__ void fc1_mfma(const ushort_t* __restrict__ X, const ushort_t* __restrict__ Wt1,
                         const float* __restrict__ b1, float* __restrict__ out) {
    int wave = threadIdx.x >> 6;
    int lane = threadIdx.x & 63;
    int quad = lane >> 4, l16 = lane & 15;
    int row0 = blockIdx.x * 64 + wave * 16;

    int arow = row0 + l16; if (arow > N_NODES - 1) arow = N_NODES - 1;
    const ushort_t* ap = X + (size_t)arow * HDIM + quad * 8;
    short8 afrag[4];
#pragma unroll
    for (int ks = 0; ks < 4; ks++) afrag[ks] = *(const short8*)(ap + ks * 32);

    floatx4 acc[3];
#pragma unroll
    for (int nt = 0; nt < 3; nt++) {
        const ushort_t* bp = Wt1 + (size_t)(nt * 16 + l16) * HDIM + quad * 8;
        floatx4 c = (floatx4){0.f, 0.f, 0.f, 0.f};
#pragma unroll
        for (int ks = 0; ks < 4; ks++) {
            short8 b = *(const short8*)(bp + ks * 32);
            c = __builtin_amdgcn_mfma_f32_16x16x32_bf16(afrag[ks], b, c, 0, 0, 0);
        }
        acc[nt] = c;
    }
#pragma unroll
    for (int nt = 0; nt < 3; nt++) {
        int col = nt * 16 + l16;
        if (col < CDIM) {
            float bias = b1[col];
#pragma unroll
            for (int r = 0; r < 4; r++) {
                int row = row0 + quad * 4 + r;
                if (row < N_NODES)
                    out[(size_t)row * CDIM + col] = acc[nt][r] + bias;
            }
        }
    }
}

// ---------------- launch ----------------

extern "C" void kernel_launch(void* const* d_in, const int* in_sizes, int n_in,
                              void* d_out, int out_size, void* d_ws, size_t ws_size,
                              hipStream_t stream) {
    const float* F     = (const float*)d_in[0];
    const int*   ei    = (const int*)d_in[1];
    const float* normA = (const float*)d_in[2];
    const float* W0    = (const float*)d_in[3];
    const float* b0    = (const float*)d_in[4];
    const float* convW = (const float*)d_in[5];
    const float* W1    = (const float*)d_in[6];
    const float* b1    = (const float*)d_in[7];
    float*       out   = (float*)d_out;

    // workspace layout (bf16 trunk), 16B-aligned
    ushort_t* h0b  = (ushort_t*)d_ws;                     // M_PAD*128
    ushort_t* xab  = h0b + (size_t)M_PAD * HDIM;
    ushort_t* xbb  = xab + (size_t)M_PAD * HDIM;
    ushort_t* Wt0  = xbb + (size_t)M_PAD * HDIM;          // 128*512
    ushort_t* WtL  = Wt0 + 128 * 512;                     // 8*128*128
    ushort_t* Wt1  = WtL + 8 * 128 * 128;                 // 48*128
    int*   row_start = (int*)(Wt1 + 48 * 128);
    int*   cursor    = row_start + (N_NODES + 8);
    int*   cnt       = cursor + (N_NODES + 8);
    int*   bsum      = cnt + (N_NODES + 8);
    int*   boff      = bsum + 256;
    int2*  perm      = (int2*)(boff + 256);               // 8B-aligned

    // CSR build
    hipMemsetAsync(cnt, 0, N_NODES * sizeof(int), stream);
    hist_kernel<<<(E_EDGES + 255) / 256, 256, 0, stream>>>(ei + E_EDGES, cnt);
    scanA<<<NB, 256, 0, stream>>>(cnt, bsum);
    scanB<<<1, 256, 0, stream>>>(bsum, boff);
    scanC<<<NB, 256, 0, stream>>>(cnt, boff, row_start, cursor);
    scatter_kernel<<<(E_EDGES + 255) / 256, 256, 0, stream>>>(ei, normA, cursor, perm);
    prep_weights<<<(128 * 512 + 8 * 128 * 128 + 48 * 128 + 255) / 256, 256, 0, stream>>>(
        W0, convW, W1, Wt0, WtL, Wt1);

    fc0_mfma<<<M_PAD / 32, 256, 0, stream>>>(F, Wt0, b0, h0b);

    // after fc0, x == h0: layer 0 reads h0b as both x and h0
    ushort_t* ping = h0b;
    ushort_t* pong = xab;
    for (int i = 0; i < LAYERS; i++) {
        float beta = logf(0.5f / (float)(i + 1) + 1.0f);
        layer_fused<<<M_PAD / 64, 256, 0, stream>>>(
            row_start, perm, ping, h0b, WtL + (size_t)i * HDIM * HDIM, pong, beta);
        if (i == 0) { ping = xab; pong = xbb; }
        else { ushort_t* tmp = ping; ping = pong; pong = tmp; }
    }
    // L0->xab, L1->xbb, ..., L7->xbb; ping == xbb here
    fc1_mfma<<<M_PAD / 64, 256, 0, stream>>>(ping, Wt1, b1, out);
}

// Round 8
// 651.094 us; speedup vs baseline: 1.1088x; 1.0499x over previous
//
#include <hip/hip_runtime.h>
#include <hip/hip_bf16.h>
#include <math.h>

#define N_NODES 50000
#define M_PAD   50048           // 782 * 64 rows; fc0 uses 1564 * 32
#define E_EDGES 800000
#define IN_DIM  512
#define HDIM    128
#define CDIM    40
#define LAYERS  8
#define NB      196             // scan blocks: ceil(50000/256)

typedef __attribute__((ext_vector_type(8))) short short8;
typedef __attribute__((ext_vector_type(4))) float floatx4;
typedef unsigned short ushort_t;

__device__ inline float bf2f(unsigned short u) {
    return __uint_as_float(((unsigned)u) << 16);
}
__device__ inline unsigned short f2bf(float v) {
    __hip_bfloat16 b = __float2bfloat16(v);
    return *reinterpret_cast<unsigned short*>(&b);
}

// ---------------- CSR build ----------------

__global__ void hist_kernel(const int* __restrict__ dst, int* __restrict__ cnt) {
    int i = blockIdx.x * blockDim.x + threadIdx.x;
    if (i < E_EDGES) atomicAdd(&cnt[dst[i]], 1);
}

__global__ void scanA(const int* __restrict__ cnt, int* __restrict__ bsum) {
    __shared__ int sm[256];
    int t = threadIdx.x, i = blockIdx.x * 256 + t;
    sm[t] = (i < N_NODES) ? cnt[i] : 0;
    __syncthreads();
    for (int d = 128; d > 0; d >>= 1) {
        if (t < d) sm[t] += sm[t + d];
        __syncthreads();
    }
    if (t == 0) bsum[blockIdx.x] = sm[0];
}

__global__ void scanB(const int* __restrict__ bsum, int* __restrict__ boff) {
    __shared__ int sm[256];
    int t = threadIdx.x;
    sm[t] = (t < NB) ? bsum[t] : 0;
    __syncthreads();
    for (int d = 1; d < 256; d <<= 1) {
        int v = (t >= d) ? sm[t - d] : 0;
        __syncthreads();
        sm[t] += v;
        __syncthreads();
    }
    if (t < NB) boff[t] = (t > 0) ? sm[t - 1] : 0;
}

__global__ void scanC(const int* __restrict__ cnt, const int* __restrict__ boff,
                      int* __restrict__ row_start, int* __restrict__ cursor) {
    __shared__ int sm[256];
    int t = threadIdx.x, i = blockIdx.x * 256 + t;
    int v = (i < N_NODES) ? cnt[i] : 0;
    sm[t] = v;
    __syncthreads();
    for (int d = 1; d < 256; d <<= 1) {
        int x = (t >= d) ? sm[t - d] : 0;
        __syncthreads();
        sm[t] += x;
        __syncthreads();
    }
    if (i < N_NODES) {
        int incl = boff[blockIdx.x] + sm[t];
        int excl = incl - v;
        row_start[i] = excl;
        cursor[i]    = excl;
        if (i == N_NODES - 1) row_start[N_NODES] = incl;
    }
}

__global__ void scatter_kernel(const int* __restrict__ ei, const float* __restrict__ normA,
                               int* __restrict__ cursor, int2* __restrict__ perm) {
    int i = blockIdx.x * blockDim.x + threadIdx.x;
    if (i >= E_EDGES) return;
    int d = ei[E_EDGES + i];
    int idx = atomicAdd(&cursor[d], 1);
    perm[idx] = make_int2(ei[i], __float_as_int(normA[i]));
}

// ---------------- weight prep: transpose + bf16 convert ----------------

__global__ void prep_weights(const float* __restrict__ W0, const float* __restrict__ convW,
                             const float* __restrict__ W1,
                             ushort_t* __restrict__ Wt0, ushort_t* __restrict__ WtL,
                             ushort_t* __restrict__ Wt1) {
    int i = blockIdx.x * blockDim.x + threadIdx.x;
    if (i < 128 * 512) {
        int n = i >> 9, k = i & 511;
        Wt0[i] = f2bf(W0[k * HDIM + n]);
        return;
    }
    int j = i - 128 * 512;
    if (j < 8 * 128 * 128) {
        int l = j >> 14, rem = j & 16383, n = rem >> 7, k = rem & 127;
        WtL[j] = f2bf(convW[l * 16384 + k * HDIM + n]);
        return;
    }
    int m = j - 8 * 128 * 128;
    if (m < 48 * 128) {
        int n = m >> 7, k = m & 127;
        Wt1[m] = (n < CDIM) ? f2bf(W1[k * CDIM + n]) : (ushort_t)0;
    }
}

// ---------------- fc0: x = relu(F @ W0 + b0) -> h0b (bf16) ----------------
// LDS-staged via global_load_lds, double-buffered 16KB chunks (round-7, ~58us).

__global__ __launch_bounds__(256)
void fc0_mfma(const float* __restrict__ F, const ushort_t* __restrict__ Wt0,
              const float* __restrict__ b0, ushort_t* __restrict__ h0b) {
    __shared__ float sA[2][32 * 128];   // 2 x 16KB
    int t = threadIdx.x;
    int wave = t >> 6, lane = t & 63;
    int quad = lane >> 4, l16 = lane & 15;
    int R0 = blockIdx.x * 32;

    const ushort_t* bbase = Wt0 + (size_t)(wave * 32 + l16) * IN_DIM + quad * 8;

    floatx4 acc[2][2];   // [rowfrag][nt]
#pragma unroll
    for (int rf = 0; rf < 2; rf++)
#pragma unroll
        for (int nt = 0; nt < 2; nt++) acc[rf][nt] = (floatx4){0.f, 0.f, 0.f, 0.f};

    auto stage = [&](int cc, int buf) {
#pragma unroll
        for (int i = 0; i < 4; i++) {
            int X = i * 4096 + wave * 1024 + lane * 16;     // byte in 16KB chunk
            int row = X >> 9;
            int colb = (X & 511) ^ ((row & 7) << 4);
            int gr = R0 + row; if (gr > N_NODES - 1) gr = N_NODES - 1;
            const float* src = F + (size_t)gr * IN_DIM + cc * 128 + (colb >> 2);
            __builtin_amdgcn_global_load_lds(
                (const __attribute__((address_space(1))) unsigned int*)src,
                (__attribute__((address_space(3))) unsigned int*)&sA[buf][i * 1024 + wave * 256],
                16, 0, 0);
        }
    };

    stage(0, 0);

    int mask = (l16 & 7) << 4;                 // per-lane read swizzle (bytes)
    int ib0 = ((quad << 5) ^ mask) >> 2;       // float offsets within ks-block
    int ib1 = (((quad << 5) | 16) ^ mask) >> 2;

#pragma unroll
    for (int cc = 0; cc < 4; cc++) {
        __syncthreads();                       // drains vmcnt -> chunk cc in LDS
        if (cc < 3) stage(cc + 1, (cc + 1) & 1);
        const float* bufp = &sA[cc & 1][0];
        const float* r0p = bufp + l16 * 128;
        const float* r1p = bufp + (l16 + 16) * 128;
#pragma unroll
        for (int k2 = 0; k2 < 4; k2++) {
            int ks = cc * 4 + k2;
            float4 f00 = *(const float4*)(r0p + k2 * 32 + ib0);
            float4 f01 = *(const float4*)(r0p + k2 * 32 + ib1);
            float4 f10 = *(const float4*)(r1p + k2 * 32 + ib0);
            float4 f11 = *(const float4*)(r1p + k2 * 32 + ib1);
            short8 a0, a1;
            a0[0] = (short)f2bf(f00.x); a0[1] = (short)f2bf(f00.y);
            a0[2] = (short)f2bf(f00.z); a0[3] = (short)f2bf(f00.w);
            a0[4] = (short)f2bf(f01.x); a0[5] = (short)f2bf(f01.y);
            a0[6] = (short)f2bf(f01.z); a0[7] = (short)f2bf(f01.w);
            a1[0] = (short)f2bf(f10.x); a1[1] = (short)f2bf(f10.y);
            a1[2] = (short)f2bf(f10.z); a1[3] = (short)f2bf(f10.w);
            a1[4] = (short)f2bf(f11.x); a1[5] = (short)f2bf(f11.y);
            a1[6] = (short)f2bf(f11.z); a1[7] = (short)f2bf(f11.w);
#pragma unroll
            for (int nt = 0; nt < 2; nt++) {
                short8 b = *(const short8*)(bbase + (size_t)nt * 16 * IN_DIM + ks * 32);
                acc[0][nt] = __builtin_amdgcn_mfma_f32_16x16x32_bf16(a0, b, acc[0][nt], 0, 0, 0);
                acc[1][nt] = __builtin_amdgcn_mfma_f32_16x16x32_bf16(a1, b, acc[1][nt], 0, 0, 0);
            }
        }
    }

#pragma unroll
    for (int nt = 0; nt < 2; nt++) {
        int col = wave * 32 + nt * 16 + l16;
        float bias = b0[col];
#pragma unroll
        for (int r = 0; r < 4; r++) {
            int row = R0 + quad * 4 + r;
            float v = acc[0][nt][r] + bias;
            v = v > 0.f ? v : 0.f;
            h0b[(size_t)row * HDIM + col] = f2bf(v);
        }
#pragma unroll
        for (int r = 0; r < 4; r++) {
            int row = R0 + 16 + quad * 4 + r;
            float v = acc[1][nt][r] + bias;
            v = v > 0.f ? v : 0.f;
            h0b[(size_t)row * HDIM + col] = f2bf(v);
        }
    }
}

// -------- fused layer: sup = 0.9*(A x)+0.1*h0 (into LDS); x' = relu(beta*(sup W)+(1-beta)*sup)
// block = 64 rows, 256 thr / 4 waves; each 16-lane group owns 4 rows serially.
// Round-8 changes (all intra-wave):
//  * NO __syncthreads(): wave w's gemm reads only sS rows [wave*16, wave*16+16)
//    which its own 4 groups wrote -- compiler's lgkmcnt ordering suffices.
//    Removes inter-wave straggler coupling; waves slide to overlap gathers.
//  * proc32: pA/pB j-blocks interleaved -> 8 independent gathers visible/iter.
//  * h0 row load issued BEFORE the gathers (used only at blend).

#define SROW 136   // 128 + 8 pad

__device__ __forceinline__ void spmm_proc32(int2 pa, int2 pb,
                                            const ushort_t* __restrict__ xb,
                                            int sl, float* __restrict__ acc) {
#pragma unroll
    for (int j = 0; j < 16; j += 4) {
        int   a0 = __shfl(pa.x, j + 0, 16), b0 = __shfl(pb.x, j + 0, 16);
        int   a1 = __shfl(pa.x, j + 1, 16), b1 = __shfl(pb.x, j + 1, 16);
        int   a2 = __shfl(pa.x, j + 2, 16), b2 = __shfl(pb.x, j + 2, 16);
        int   a3 = __shfl(pa.x, j + 3, 16), b3 = __shfl(pb.x, j + 3, 16);
        float wa0 = __int_as_float(__shfl(pa.y, j + 0, 16));
        float wa1 = __int_as_float(__shfl(pa.y, j + 1, 16));
        float wa2 = __int_as_float(__shfl(pa.y, j + 2, 16));
        float wa3 = __int_as_float(__shfl(pa.y, j + 3, 16));
        float wb0 = __int_as_float(__shfl(pb.y, j + 0, 16));
        float wb1 = __int_as_float(__shfl(pb.y, j + 1, 16));
        float wb2 = __int_as_float(__shfl(pb.y, j + 2, 16));
        float wb3 = __int_as_float(__shfl(pb.y, j + 3, 16));
        short8 va0 = *(const short8*)(xb + (size_t)a0 * HDIM + sl * 8);
        short8 vb0 = *(const short8*)(xb + (size_t)b0 * HDIM + sl * 8);
        short8 va1 = *(const short8*)(xb + (size_t)a1 * HDIM + sl * 8);
        short8 vb1 = *(const short8*)(xb + (size_t)b1 * HDIM + sl * 8);
        short8 va2 = *(const short8*)(xb + (size_t)a2 * HDIM + sl * 8);
        short8 vb2 = *(const short8*)(xb + (size_t)b2 * HDIM + sl * 8);
        short8 va3 = *(const short8*)(xb + (size_t)a3 * HDIM + sl * 8);
        short8 vb3 = *(const short8*)(xb + (size_t)b3 * HDIM + sl * 8);
#pragma unroll
        for (int c = 0; c < 8; c++) {
            acc[c] += wa0 * bf2f((ushort_t)va0[c]);
            acc[c] += wa1 * bf2f((ushort_t)va1[c]);
            acc[c] += wa2 * bf2f((ushort_t)va2[c]);
            acc[c] += wa3 * bf2f((ushort_t)va3[c]);
            acc[c] += wb0 * bf2f((ushort_t)vb0[c]);
            acc[c] += wb1 * bf2f((ushort_t)vb1[c]);
            acc[c] += wb2 * bf2f((ushort_t)vb2[c]);
            acc[c] += wb3 * bf2f((ushort_t)vb3[c]);
        }
    }
}

__global__ __launch_bounds__(256)
void layer_fused(const int* __restrict__ row_start, const int2* __restrict__ perm,
                 const ushort_t* __restrict__ xb, const ushort_t* __restrict__ h0b,
                 const ushort_t* __restrict__ Wt, ushort_t* __restrict__ X,
                 float beta) {
    __shared__ short sS[64][SROW];   // 17.4 KB; wave-private 16-row slices
    int t = threadIdx.x;
    int wave = t >> 6, lane = t & 63;
    int grp = lane >> 4, sl = lane & 15;
    int quad = lane >> 4, l16 = lane & 15;   // gemm aliases
    int row0 = blockIdx.x * 64;
    int G = wave * 4 + grp;                  // block-local group 0..15
    int Rg = row0 + G * 4;                   // 4 rows per group

    // row bounds for this group's 4 rows: one lane-parallel load + shfl
    int rbv = 0;
    if (sl <= 4) {
        int idx = Rg + sl; if (idx > N_NODES) idx = N_NODES;
        rbv = row_start[idx];
    }
    int e0[4], e1[4];
#pragma unroll
    for (int r = 0; r < 4; r++) {
        e0[r] = __shfl(rbv, r, 16);
        e1[r] = __shfl(rbv, r + 1, 16);
    }

    // prefetch row 0's chunk-0 perm entries
    int2 pA = make_int2(0, 0), pB = make_int2(0, 0);
    if (e0[0] + sl < e1[0])      pA = perm[e0[0] + sl];
    if (e0[0] + 16 + sl < e1[0]) pB = perm[e0[0] + 16 + sl];

#pragma unroll
    for (int r = 0; r < 4; r++) {
        int row = Rg + r;

        // issue h0 load early (consumed only at blend)
        short8 h;
#pragma unroll
        for (int c = 0; c < 8; c++) h[c] = 0;
        if (row < N_NODES) h = *(const short8*)(h0b + (size_t)row * HDIM + sl * 8);

        // prefetch next row's perm before touching this row's gathers
        int2 nA = make_int2(0, 0), nB = make_int2(0, 0);
        if (r < 3) {
            if (e0[r + 1] + sl < e1[r + 1])      nA = perm[e0[r + 1] + sl];
            if (e0[r + 1] + 16 + sl < e1[r + 1]) nB = perm[e0[r + 1] + 16 + sl];
        }

        float acc[8];
#pragma unroll
        for (int c = 0; c < 8; c++) acc[c] = 0.f;

        spmm_proc32(pA, pB, xb, sl, acc);

        // rare tails (degree > 32)
        for (int chunk = e0[r] + 32; chunk < e1[r]; chunk += 32) {
            int2 qa = make_int2(0, 0), qb = make_int2(0, 0);
            if (chunk + sl < e1[r])      qa = perm[chunk + sl];
            if (chunk + 16 + sl < e1[r]) qb = perm[chunk + 16 + sl];
            spmm_proc32(qa, qb, xb, sl, acc);
        }

        // blend with h0 and stage to LDS (acc dies here)
        short8 o;
        if (row < N_NODES) {
#pragma unroll
            for (int c = 0; c < 8; c++)
                o[c] = (short)f2bf(0.9f * acc[c] + 0.1f * bf2f((ushort_t)h[c]));
        } else {
#pragma unroll
            for (int c = 0; c < 8; c++) o[c] = 0;
        }
        *(short8*)&sS[G * 4 + r][sl * 8] = o;

        pA = nA; pB = nB;
    }
    // NO __syncthreads(): gemm below consumes only this wave's own sS rows.

    // ---- gemm phase ----
    short8 afrag[4];
#pragma unroll
    for (int ks = 0; ks < 4; ks++)
        afrag[ks] = *(const short8*)&sS[wave * 16 + l16][ks * 32 + quad * 8];

    floatx4 gacc[8];
#pragma unroll
    for (int nt = 0; nt < 8; nt++) {
        const ushort_t* bp = Wt + (size_t)(nt * 16 + l16) * HDIM + quad * 8;
        floatx4 c = (floatx4){0.f, 0.f, 0.f, 0.f};
#pragma unroll
        for (int ks = 0; ks < 4; ks++) {
            short8 b = *(const short8*)(bp + ks * 32);
            c = __builtin_amdgcn_mfma_f32_16x16x32_bf16(afrag[ks], b, c, 0, 0, 0);
        }
        gacc[nt] = c;
    }
    float g = 1.f - beta;
#pragma unroll
    for (int nt = 0; nt < 8; nt++) {
        int col = nt * 16 + l16;
#pragma unroll
        for (int r = 0; r < 4; r++) {
            int lrow = wave * 16 + quad * 4 + r;
            float s = bf2f((ushort_t)sS[lrow][col]);
            float v = beta * gacc[nt][r] + g * s;
            v = v > 0.f ? v : 0.f;
            X[(size_t)(row0 + lrow) * HDIM + col] = f2bf(v);
        }
    }
}

// ---------------- fc1: out = x @ W1 + b1 (fp32 out), N padded 40->48 ----------------

__global__ void fc1_mfma(const ushort_t* __restrict__ X, const ushort_t* __restrict__ Wt1,
                         const float* __restrict__ b1, float* __restrict__ out) {
    int wave = threadIdx.x >> 6;
    int lane = threadIdx.x & 63;
    int quad = lane >> 4, l16 = lane & 15;
    int row0 = blockIdx.x * 64 + wave * 16;

    int arow = row0 + l16; if (arow > N_NODES - 1) arow = N_NODES - 1;
    const ushort_t* ap = X + (size_t)arow * HDIM + quad * 8;
    short8 afrag[4];
#pragma unroll
    for (int ks = 0; ks < 4; ks++) afrag[ks] = *(const short8*)(ap + ks * 32);

    floatx4 acc[3];
#pragma unroll
    for (int nt = 0; nt < 3; nt++) {
        const ushort_t* bp = Wt1 + (size_t)(nt * 16 + l16) * HDIM + quad * 8;
        floatx4 c = (floatx4){0.f, 0.f, 0.f, 0.f};
#pragma unroll
        for (int ks = 0; ks < 4; ks++) {
            short8 b = *(const short8*)(bp + ks * 32);
            c = __builtin_amdgcn_mfma_f32_16x16x32_bf16(afrag[ks], b, c, 0, 0, 0);
        }
        acc[nt] = c;
    }
#pragma unroll
    for (int nt = 0; nt < 3; nt++) {
        int col = nt * 16 + l16;
        if (col < CDIM) {
            float bias = b1[col];
#pragma unroll
            for (int r = 0; r < 4; r++) {
                int row = row0 + quad * 4 + r;
                if (row < N_NODES)
                    out[(size_t)row * CDIM + col] = acc[nt][r] + bias;
            }
        }
    }
}

// ---------------- launch ----------------

extern "C" void kernel_launch(void* const* d_in, const int* in_sizes, int n_in,
                              void* d_out, int out_size, void* d_ws, size_t ws_size,
                              hipStream_t stream) {
    const float* F     = (const float*)d_in[0];
    const int*   ei    = (const int*)d_in[1];
    const float* normA = (const float*)d_in[2];
    const float* W0    = (const float*)d_in[3];
    const float* b0    = (const float*)d_in[4];
    const float* convW = (const float*)d_in[5];
    const float* W1    = (const float*)d_in[6];
    const float* b1    = (const float*)d_in[7];
    float*       out   = (float*)d_out;

    // workspace layout (bf16 trunk), 16B-aligned
    ushort_t* h0b  = (ushort_t*)d_ws;                     // M_PAD*128
    ushort_t* xab  = h0b + (size_t)M_PAD * HDIM;
    ushort_t* xbb  = xab + (size_t)M_PAD * HDIM;
    ushort_t* Wt0  = xbb + (size_t)M_PAD * HDIM;          // 128*512
    ushort_t* WtL  = Wt0 + 128 * 512;                     // 8*128*128
    ushort_t* Wt1  = WtL + 8 * 128 * 128;                 // 48*128
    int*   row_start = (int*)(Wt1 + 48 * 128);
    int*   cursor    = row_start + (N_NODES + 8);
    int*   cnt       = cursor + (N_NODES + 8);
    int*   bsum      = cnt + (N_NODES + 8);
    int*   boff      = bsum + 256;
    int2*  perm      = (int2*)(boff + 256);               // 8B-aligned

    // CSR build
    hipMemsetAsync(cnt, 0, N_NODES * sizeof(int), stream);
    hist_kernel<<<(E_EDGES + 255) / 256, 256, 0, stream>>>(ei + E_EDGES, cnt);
    scanA<<<NB, 256, 0, stream>>>(cnt, bsum);
    scanB<<<1, 256, 0, stream>>>(bsum, boff);
    scanC<<<NB, 256, 0, stream>>>(cnt, boff, row_start, cursor);
    scatter_kernel<<<(E_EDGES + 255) / 256, 256, 0, stream>>>(ei, normA, cursor, perm);
    prep_weights<<<(128 * 512 + 8 * 128 * 128 + 48 * 128 + 255) / 256, 256, 0, stream>>>(
        W0, convW, W1, Wt0, WtL, Wt1);

    fc0_mfma<<<M_PAD / 32, 256, 0, stream>>>(F, Wt0, b0, h0b);

    // after fc0, x == h0: layer 0 reads h0b as both x and h0
    ushort_t* ping = h0b;
    ushort_t* pong = xab;
    for (int i = 0; i < LAYERS; i++) {
        float beta = logf(0.5f / (float)(i + 1) + 1.0f);
        layer_fused<<<M_PAD / 64, 256, 0, stream>>>(
            row_start, perm, ping, h0b, WtL + (size_t)i * HDIM * HDIM, pong, beta);
        if (i == 0) { ping = xab; pong = xbb; }
        else { ushort_t* tmp = ping; ping = pong; pong = tmp; }
    }
    // L0->xab, L1->xbb, ..., L7->xbb; ping == xbb here
    fc1_mfma<<<M_PAD / 64, 256, 0, stream>>>(ping, Wt1, b1, out);
}

// Round 9
// 645.602 us; speedup vs baseline: 1.1183x; 1.0085x over previous
//
#include <hip/hip_runtime.h>
#include <hip/hip_bf16.h>
#include <math.h>

#define N_NODES 50000
#define M_PAD   50048           // 782 * 64 rows; fc0 uses 1564 * 32
#define E_EDGES 800000
#define IN_DIM  512
#define HDIM    128
#define CDIM    40
#define LAYERS  8
#define NB      196             // scan blocks: ceil(50000/256)

typedef __attribute__((ext_vector_type(8))) short short8;
typedef __attribute__((ext_vector_type(4))) float floatx4;
typedef unsigned short ushort_t;

__device__ inline float bf2f(unsigned short u) {
    return __uint_as_float(((unsigned)u) << 16);
}
__device__ inline unsigned short f2bf(float v) {
    __hip_bfloat16 b = __float2bfloat16(v);
    return *reinterpret_cast<unsigned short*>(&b);
}

// ---------------- CSR build ----------------

__global__ void hist_kernel(const int* __restrict__ dst, int* __restrict__ cnt) {
    int i = blockIdx.x * blockDim.x + threadIdx.x;
    if (i < E_EDGES) atomicAdd(&cnt[dst[i]], 1);
}

__global__ void scanA(const int* __restrict__ cnt, int* __restrict__ bsum) {
    __shared__ int sm[256];
    int t = threadIdx.x, i = blockIdx.x * 256 + t;
    sm[t] = (i < N_NODES) ? cnt[i] : 0;
    __syncthreads();
    for (int d = 128; d > 0; d >>= 1) {
        if (t < d) sm[t] += sm[t + d];
        __syncthreads();
    }
    if (t == 0) bsum[blockIdx.x] = sm[0];
}

__global__ void scanB(const int* __restrict__ bsum, int* __restrict__ boff) {
    __shared__ int sm[256];
    int t = threadIdx.x;
    sm[t] = (t < NB) ? bsum[t] : 0;
    __syncthreads();
    for (int d = 1; d < 256; d <<= 1) {
        int v = (t >= d) ? sm[t - d] : 0;
        __syncthreads();
        sm[t] += v;
        __syncthreads();
    }
    if (t < NB) boff[t] = (t > 0) ? sm[t - 1] : 0;
}

__global__ void scanC(const int* __restrict__ cnt, const int* __restrict__ boff,
                      int* __restrict__ row_start, int* __restrict__ cursor) {
    __shared__ int sm[256];
    int t = threadIdx.x, i = blockIdx.x * 256 + t;
    int v = (i < N_NODES) ? cnt[i] : 0;
    sm[t] = v;
    __syncthreads();
    for (int d = 1; d < 256; d <<= 1) {
        int x = (t >= d) ? sm[t - d] : 0;
        __syncthreads();
        sm[t] += x;
        __syncthreads();
    }
    if (i < N_NODES) {
        int incl = boff[blockIdx.x] + sm[t];
        int excl = incl - v;
        row_start[i] = excl;
        cursor[i]    = excl;
        if (i == N_NODES - 1) row_start[N_NODES] = incl;
    }
}

__global__ void scatter_kernel(const int* __restrict__ ei, const float* __restrict__ normA,
                               int* __restrict__ cursor, int2* __restrict__ perm) {
    int i = blockIdx.x * blockDim.x + threadIdx.x;
    if (i >= E_EDGES) return;
    int d = ei[E_EDGES + i];
    int idx = atomicAdd(&cursor[d], 1);
    perm[idx] = make_int2(ei[i], __float_as_int(normA[i]));
}

// ---------------- weight prep: transpose + bf16 convert ----------------

__global__ void prep_weights(const float* __restrict__ W0, const float* __restrict__ convW,
                             const float* __restrict__ W1,
                             ushort_t* __restrict__ Wt0, ushort_t* __restrict__ WtL,
                             ushort_t* __restrict__ Wt1) {
    int i = blockIdx.x * blockDim.x + threadIdx.x;
    if (i < 128 * 512) {
        int n = i >> 9, k = i & 511;
        Wt0[i] = f2bf(W0[k * HDIM + n]);
        return;
    }
    int j = i - 128 * 512;
    if (j < 8 * 128 * 128) {
        int l = j >> 14, rem = j & 16383, n = rem >> 7, k = rem & 127;
        WtL[j] = f2bf(convW[l * 16384 + k * HDIM + n]);
        return;
    }
    int m = j - 8 * 128 * 128;
    if (m < 48 * 128) {
        int n = m >> 7, k = m & 127;
        Wt1[m] = (n < CDIM) ? f2bf(W1[k * CDIM + n]) : (ushort_t)0;
    }
}

// ---------------- fc0: x = relu(F @ W0 + b0) -> h0b (bf16) ----------------
// Round-9: counted-vmcnt pipeline. __syncthreads emitted s_waitcnt vmcnt(0)
// which drained the just-staged next chunk every iteration (depth-1 collapse,
// ~500cy exposed per chunk). Now: TRIPLE buffer (48KB) + raw s_barrier +
// asm vmcnt(4). In-order vmcnt retirement: at iter cc, stage(cc) is older
// than stage(cc+1)+B-loads (>=4 newer ops), so "<=4 outstanding" implies
// chunk cc landed while chunks cc+1 / cc+2 stay in flight (true depth-2).

__global__ __launch_bounds__(256)
void fc0_mfma(const float* __restrict__ F, const ushort_t* __restrict__ Wt0,
              const float* __restrict__ b0, ushort_t* __restrict__ h0b) {
    __shared__ float sA[3][32 * 128];   // 3 x 16KB
    int t = threadIdx.x;
    int wave = t >> 6, lane = t & 63;
    int quad = lane >> 4, l16 = lane & 15;
    int R0 = blockIdx.x * 32;

    const ushort_t* bbase = Wt0 + (size_t)(wave * 32 + l16) * IN_DIM + quad * 8;

    floatx4 acc[2][2];   // [rowfrag][nt]
#pragma unroll
    for (int rf = 0; rf < 2; rf++)
#pragma unroll
        for (int nt = 0; nt < 2; nt++) acc[rf][nt] = (floatx4){0.f, 0.f, 0.f, 0.f};

    auto stage = [&](int cc, int buf) {
#pragma unroll
        for (int i = 0; i < 4; i++) {
            int X = i * 4096 + wave * 1024 + lane * 16;     // byte in 16KB chunk
            int row = X >> 9;
            int colb = (X & 511) ^ ((row & 7) << 4);
            int gr = R0 + row; if (gr > N_NODES - 1) gr = N_NODES - 1;
            const float* src = F + (size_t)gr * IN_DIM + cc * 128 + (colb >> 2);
            __builtin_amdgcn_global_load_lds(
                (const __attribute__((address_space(1))) unsigned int*)src,
                (__attribute__((address_space(3))) unsigned int*)&sA[buf][i * 1024 + wave * 256],
                16, 0, 0);
        }
    };

    stage(0, 0);
    stage(1, 1);

    int mask = (l16 & 7) << 4;                 // per-lane read swizzle (bytes)
    int ib0 = ((quad << 5) ^ mask) >> 2;       // float offsets within ks-block
    int ib1 = (((quad << 5) | 16) ^ mask) >> 2;

#pragma unroll
    for (int cc = 0; cc < 4; cc++) {
        asm volatile("s_waitcnt vmcnt(4)" ::: "memory");   // chunk cc landed (in-order)
        __builtin_amdgcn_s_barrier();
        __builtin_amdgcn_sched_barrier(0);
        if (cc < 2) stage(cc + 2, (cc + 2) % 3);
        const float* bufp = &sA[cc % 3][0];
        const float* r0p = bufp + l16 * 128;
        const float* r1p = bufp + (l16 + 16) * 128;
#pragma unroll
        for (int k2 = 0; k2 < 4; k2++) {
            int ks = cc * 4 + k2;
            float4 f00 = *(const float4*)(r0p + k2 * 32 + ib0);
            float4 f01 = *(const float4*)(r0p + k2 * 32 + ib1);
            float4 f10 = *(const float4*)(r1p + k2 * 32 + ib0);
            float4 f11 = *(const float4*)(r1p + k2 * 32 + ib1);
            short8 a0, a1;
            a0[0] = (short)f2bf(f00.x); a0[1] = (short)f2bf(f00.y);
            a0[2] = (short)f2bf(f00.z); a0[3] = (short)f2bf(f00.w);
            a0[4] = (short)f2bf(f01.x); a0[5] = (short)f2bf(f01.y);
            a0[6] = (short)f2bf(f01.z); a0[7] = (short)f2bf(f01.w);
            a1[0] = (short)f2bf(f10.x); a1[1] = (short)f2bf(f10.y);
            a1[2] = (short)f2bf(f10.z); a1[3] = (short)f2bf(f10.w);
            a1[4] = (short)f2bf(f11.x); a1[5] = (short)f2bf(f11.y);
            a1[6] = (short)f2bf(f11.z); a1[7] = (short)f2bf(f11.w);
#pragma unroll
            for (int nt = 0; nt < 2; nt++) {
                short8 b = *(const short8*)(bbase + (size_t)nt * 16 * IN_DIM + ks * 32);
                acc[0][nt] = __builtin_amdgcn_mfma_f32_16x16x32_bf16(a0, b, acc[0][nt], 0, 0, 0);
                acc[1][nt] = __builtin_amdgcn_mfma_f32_16x16x32_bf16(a1, b, acc[1][nt], 0, 0, 0);
            }
        }
    }

#pragma unroll
    for (int nt = 0; nt < 2; nt++) {
        int col = wave * 32 + nt * 16 + l16;
        float bias = b0[col];
#pragma unroll
        for (int r = 0; r < 4; r++) {
            int row = R0 + quad * 4 + r;
            float v = acc[0][nt][r] + bias;
            v = v > 0.f ? v : 0.f;
            h0b[(size_t)row * HDIM + col] = f2bf(v);
        }
#pragma unroll
        for (int r = 0; r < 4; r++) {
            int row = R0 + 16 + quad * 4 + r;
            float v = acc[1][nt][r] + bias;
            v = v > 0.f ? v : 0.f;
            h0b[(size_t)row * HDIM + col] = f2bf(v);
        }
    }
}

// -------- fused layer: sup = 0.9*(A x)+0.1*h0 (into LDS); x' = relu(beta*(sup W)+(1-beta)*sup)
// block = 64 rows, 256 thr / 4 waves; each 16-lane group owns 4 rows serially;
// no barrier (wave-private sS slices). Round-9: DYNAMIC edge trip count --
// mean degree 16 vs fixed 32 slots meant ~half the gathers/FMAs were w=0
// waste; now loop j < min(deg,32) step 8 (wave runs max over its 4 groups,
// ~24 slots instead of 32).

#define SROW 136   // 128 + 8 pad

__device__ __forceinline__ void spmm_proc32(int2 pa, int2 pb,
                                            const ushort_t* __restrict__ xb,
                                            int sl, float* __restrict__ acc) {
#pragma unroll
    for (int j = 0; j < 16; j += 4) {
        int   a0 = __shfl(pa.x, j + 0, 16), b0 = __shfl(pb.x, j + 0, 16);
        int   a1 = __shfl(pa.x, j + 1, 16), b1 = __shfl(pb.x, j + 1, 16);
        int   a2 = __shfl(pa.x, j + 2, 16), b2 = __shfl(pb.x, j + 2, 16);
        int   a3 = __shfl(pa.x, j + 3, 16), b3 = __shfl(pb.x, j + 3, 16);
        float wa0 = __int_as_float(__shfl(pa.y, j + 0, 16));
        float wa1 = __int_as_float(__shfl(pa.y, j + 1, 16));
        float wa2 = __int_as_float(__shfl(pa.y, j + 2, 16));
        float wa3 = __int_as_float(__shfl(pa.y, j + 3, 16));
        float wb0 = __int_as_float(__shfl(pb.y, j + 0, 16));
        float wb1 = __int_as_float(__shfl(pb.y, j + 1, 16));
        float wb2 = __int_as_float(__shfl(pb.y, j + 2, 16));
        float wb3 = __int_as_float(__shfl(pb.y, j + 3, 16));
        short8 va0 = *(const short8*)(xb + (size_t)a0 * HDIM + sl * 8);
        short8 vb0 = *(const short8*)(xb + (size_t)b0 * HDIM + sl * 8);
        short8 va1 = *(const short8*)(xb + (size_t)a1 * HDIM + sl * 8);
        short8 vb1 = *(const short8*)(xb + (size_t)b1 * HDIM + sl * 8);
        short8 va2 = *(const short8*)(xb + (size_t)a2 * HDIM + sl * 8);
        short8 vb2 = *(const short8*)(xb + (size_t)b2 * HDIM + sl * 8);
        short8 va3 = *(const short8*)(xb + (size_t)a3 * HDIM + sl * 8);
        short8 vb3 = *(const short8*)(xb + (size_t)b3 * HDIM + sl * 8);
#pragma unroll
        for (int c = 0; c < 8; c++) {
            acc[c] += wa0 * bf2f((ushort_t)va0[c]);
            acc[c] += wa1 * bf2f((ushort_t)va1[c]);
            acc[c] += wa2 * bf2f((ushort_t)va2[c]);
            acc[c] += wa3 * bf2f((ushort_t)va3[c]);
            acc[c] += wb0 * bf2f((ushort_t)vb0[c]);
            acc[c] += wb1 * bf2f((ushort_t)vb1[c]);
            acc[c] += wb2 * bf2f((ushort_t)vb2[c]);
            acc[c] += wb3 * bf2f((ushort_t)vb3[c]);
        }
    }
}

__global__ __launch_bounds__(256)
void layer_fused(const int* __restrict__ row_start, const int2* __restrict__ perm,
                 const ushort_t* __restrict__ xb, const ushort_t* __restrict__ h0b,
                 const ushort_t* __restrict__ Wt, ushort_t* __restrict__ X,
                 float beta) {
    __shared__ short sS[64][SROW];   // 17.4 KB; wave-private 16-row slices
    int t = threadIdx.x;
    int wave = t >> 6, lane = t & 63;
    int grp = lane >> 4, sl = lane & 15;
    int quad = lane >> 4, l16 = lane & 15;   // gemm aliases
    int row0 = blockIdx.x * 64;
    int G = wave * 4 + grp;                  // block-local group 0..15
    int Rg = row0 + G * 4;                   // 4 rows per group

    // row bounds for this group's 4 rows: one lane-parallel load + shfl
    int rbv = 0;
    if (sl <= 4) {
        int idx = Rg + sl; if (idx > N_NODES) idx = N_NODES;
        rbv = row_start[idx];
    }
    int e0[4], e1[4];
#pragma unroll
    for (int r = 0; r < 4; r++) {
        e0[r] = __shfl(rbv, r, 16);
        e1[r] = __shfl(rbv, r + 1, 16);
    }

    // prefetch row 0's chunk-0 perm entries
    int2 pA = make_int2(0, 0), pB = make_int2(0, 0);
    if (e0[0] + sl < e1[0])      pA = perm[e0[0] + sl];
    if (e0[0] + 16 + sl < e1[0]) pB = perm[e0[0] + 16 + sl];

#pragma unroll
    for (int r = 0; r < 4; r++) {
        int row = Rg + r;

        // issue h0 load early (consumed only at blend)
        short8 h;
#pragma unroll
        for (int c = 0; c < 8; c++) h[c] = 0;
        if (row < N_NODES) h = *(const short8*)(h0b + (size_t)row * HDIM + sl * 8);

        // prefetch next row's perm before touching this row's gathers
        int2 nA = make_int2(0, 0), nB = make_int2(0, 0);
        if (r < 3) {
            if (e0[r + 1] + sl < e1[r + 1])      nA = perm[e0[r + 1] + sl];
            if (e0[r + 1] + 16 + sl < e1[r + 1]) nB = perm[e0[r + 1] + 16 + sl];
        }

        float acc[8];
#pragma unroll
        for (int c = 0; c < 8; c++) acc[c] = 0.f;

        // dynamic trip count: only ceil(min(deg,32)/8)*8 slots touched;
        // slots >= deg carry pm=(0,0) -> w=0, harmless.
        int deg = e1[r] - e0[r];
        int n = deg < 32 ? deg : 32;
        for (int j = 0; j < n; j += 8) {
            int2 pL = (j < 16) ? pA : pB;
            int2 pH = (j + 4 < 16) ? pA : pB;
            int jl = j & 15, jh = (j + 4) & 15;
            int   a0 = __shfl(pL.x, jl + 0, 16), b0 = __shfl(pH.x, jh + 0, 16);
            int   a1 = __shfl(pL.x, jl + 1, 16), b1 = __shfl(pH.x, jh + 1, 16);
            int   a2 = __shfl(pL.x, jl + 2, 16), b2 = __shfl(pH.x, jh + 2, 16);
            int   a3 = __shfl(pL.x, jl + 3, 16), b3 = __shfl(pH.x, jh + 3, 16);
            float wa0 = __int_as_float(__shfl(pL.y, jl + 0, 16));
            float wa1 = __int_as_float(__shfl(pL.y, jl + 1, 16));
            float wa2 = __int_as_float(__shfl(pL.y, jl + 2, 16));
            float wa3 = __int_as_float(__shfl(pL.y, jl + 3, 16));
            float wb0 = __int_as_float(__shfl(pH.y, jh + 0, 16));
            float wb1 = __int_as_float(__shfl(pH.y, jh + 1, 16));
            float wb2 = __int_as_float(__shfl(pH.y, jh + 2, 16));
            float wb3 = __int_as_float(__shfl(pH.y, jh + 3, 16));
            short8 va0 = *(const short8*)(xb + (size_t)a0 * HDIM + sl * 8);
            short8 vb0 = *(const short8*)(xb + (size_t)b0 * HDIM + sl * 8);
            short8 va1 = *(const short8*)(xb + (size_t)a1 * HDIM + sl * 8);
            short8 vb1 = *(const short8*)(xb + (size_t)b1 * HDIM + sl * 8);
            short8 va2 = *(const short8*)(xb + (size_t)a2 * HDIM + sl * 8);
            short8 vb2 = *(const short8*)(xb + (size_t)b2 * HDIM + sl * 8);
            short8 va3 = *(const short8*)(xb + (size_t)a3 * HDIM + sl * 8);
            short8 vb3 = *(const short8*)(xb + (size_t)b3 * HDIM + sl * 8);
#pragma unroll
            for (int c = 0; c < 8; c++) {
                acc[c] += wa0 * bf2f((ushort_t)va0[c]);
                acc[c] += wa1 * bf2f((ushort_t)va1[c]);
                acc[c] += wa2 * bf2f((ushort_t)va2[c]);
                acc[c] += wa3 * bf2f((ushort_t)va3[c]);
                acc[c] += wb0 * bf2f((ushort_t)vb0[c]);
                acc[c] += wb1 * bf2f((ushort_t)vb1[c]);
                acc[c] += wb2 * bf2f((ushort_t)vb2[c]);
                acc[c] += wb3 * bf2f((ushort_t)vb3[c]);
            }
        }

        // rare tails (degree > 32)
        for (int chunk = e0[r] + 32; chunk < e1[r]; chunk += 32) {
            int2 qa = make_int2(0, 0), qb = make_int2(0, 0);
            if (chunk + sl < e1[r])      qa = perm[chunk + sl];
            if (chunk + 16 + sl < e1[r]) qb = perm[chunk + 16 + sl];
            spmm_proc32(qa, qb, xb, sl, acc);
        }

        // blend with h0 and stage to LDS (acc dies here)
        short8 o;
        if (row < N_NODES) {
#pragma unroll
            for (int c = 0; c < 8; c++)
                o[c] = (short)f2bf(0.9f * acc[c] + 0.1f * bf2f((ushort_t)h[c]));
        } else {
#pragma unroll
            for (int c = 0; c < 8; c++) o[c] = 0;
        }
        *(short8*)&sS[G * 4 + r][sl * 8] = o;

        pA = nA; pB = nB;
    }
    // NO __syncthreads(): gemm below consumes only this wave's own sS rows.

    // ---- gemm phase ----
    short8 afrag[4];
#pragma unroll
    for (int ks = 0; ks < 4; ks++)
        afrag[ks] = *(const short8*)&sS[wave * 16 + l16][ks * 32 + quad * 8];

    floatx4 gacc[8];
#pragma unroll
    for (int nt = 0; nt < 8; nt++) {
        const ushort_t* bp = Wt + (size_t)(nt * 16 + l16) * HDIM + quad * 8;
        floatx4 c = (floatx4){0.f, 0.f, 0.f, 0.f};
#pragma unroll
        for (int ks = 0; ks < 4; ks++) {
            short8 b = *(const short8*)(bp + ks * 32);
            c = __builtin_amdgcn_mfma_f32_16x16x32_bf16(afrag[ks], b, c, 0, 0, 0);
        }
        gacc[nt] = c;
    }
    float g = 1.f - beta;
#pragma unroll
    for (int nt = 0; nt < 8; nt++) {
        int col = nt * 16 + l16;
#pragma unroll
        for (int r = 0; r < 4; r++) {
            int lrow = wave * 16 + quad * 4 + r;
            float s = bf2f((ushort_t)sS[lrow][col]);
            float v = beta * gacc[nt][r] + g * s;
            v = v > 0.f ? v : 0.f;
            X[(size_t)(row0 + lrow) * HDIM + col] = f2bf(v);
        }
    }
}

// ---------------- fc1: out = x @ W1 + b1 (fp32 out), N padded 40->48 ----------------

__global__ void fc1_mfma(const ushort_t* __restrict__ X, const ushort_t* __restrict__ Wt1,
                         const float* __restrict__ b1, float* __restrict__ out) {
    int wave = threadIdx.x >> 6;
    int lane = threadIdx.x & 63;
    int quad = lane >> 4, l16 = lane & 15;
    int row0 = blockIdx.x * 64 + wave * 16;

    int arow = row0 + l16; if (arow > N_NODES - 1) arow = N_NODES - 1;
    const ushort_t* ap = X + (size_t)arow * HDIM + quad * 8;
    short8 afrag[4];
#pragma unroll
    for (int ks = 0; ks < 4; ks++) afrag[ks] = *(const short8*)(ap + ks * 32);

    floatx4 acc[3];
#pragma unroll
    for (int nt = 0; nt < 3; nt++) {
        const ushort_t* bp = Wt1 + (size_t)(nt * 16 + l16) * HDIM + quad * 8;
        floatx4 c = (floatx4){0.f, 0.f, 0.f, 0.f};
#pragma unroll
        for (int ks = 0; ks < 4; ks++) {
            short8 b = *(const short8*)(bp + ks * 32);
            c = __builtin_amdgcn_mfma_f32_16x16x32_bf16(afrag[ks], b, c, 0, 0, 0);
        }
        acc[nt] = c;
    }
#pragma unroll
    for (int nt = 0; nt < 3; nt++) {
        int col = nt * 16 + l16;
        if (col < CDIM) {
            float bias = b1[col];
#pragma unroll
            for (int r = 0; r < 4; r++) {
                int row = row0 + quad * 4 + r;
                if (row < N_NODES)
                    out[(size_t)row * CDIM + col] = acc[nt][r] + bias;
            }
        }
    }
}

// ---------------- launch ----------------

extern "C" void kernel_launch(void* const* d_in, const int* in_sizes, int n_in,
                              void* d_out, int out_size, void* d_ws, size_t ws_size,
                              hipStream_t stream) {
    const float* F     = (const float*)d_in[0];
    const int*   ei    = (const int*)d_in[1];
    const float* normA = (const float*)d_in[2];
    const float* W0    = (const float*)d_in[3];
    const float* b0    = (const float*)d_in[4];
    const float* convW = (const float*)d_in[5];
    const float* W1    = (const float*)d_in[6];
    const float* b1    = (const float*)d_in[7];
    float*       out   = (float*)d_out;

    // workspace layout (bf16 trunk), 16B-aligned
    ushort_t* h0b  = (ushort_t*)d_ws;                     // M_PAD*128
    ushort_t* xab  = h0b + (size_t)M_PAD * HDIM;
    ushort_t* xbb  = xab + (size_t)M_PAD * HDIM;
    ushort_t* Wt0  = xbb + (size_t)M_PAD * HDIM;          // 128*512
    ushort_t* WtL  = Wt0 + 128 * 512;                     // 8*128*128
    ushort_t* Wt1  = WtL + 8 * 128 * 128;                 // 48*128
    int*   row_start = (int*)(Wt1 + 48 * 128);
    int*   cursor    = row_start + (N_NODES + 8);
    int*   cnt       = cursor + (N_NODES + 8);
    int*   bsum      = cnt + (N_NODES + 8);
    int*   boff      = bsum + 256;
    int2*  perm      = (int2*)(boff + 256);               // 8B-aligned

    // CSR build
    hipMemsetAsync(cnt, 0, N_NODES * sizeof(int), stream);
    hist_kernel<<<(E_EDGES + 255) / 256, 256, 0, stream>>>(ei + E_EDGES, cnt);
    scanA<<<NB, 256, 0, stream>>>(cnt, bsum);
    scanB<<<1, 256, 0, stream>>>(bsum, boff);
    scanC<<<NB, 256, 0, stream>>>(cnt, boff, row_start, cursor);
    scatter_kernel<<<(E_EDGES + 255) / 256, 256, 0, stream>>>(ei, normA, cursor, perm);
    prep_weights<<<(128 * 512 + 8 * 128 * 128 + 48 * 128 + 255) / 256, 256, 0, stream>>>(
        W0, convW, W1, Wt0, WtL, Wt1);

    fc0_mfma<<<M_PAD / 32, 256, 0, stream>>>(F, Wt0, b0, h0b);

    // after fc0, x == h0: layer 0 reads h0b as both x and h0
    ushort_t* ping = h0b;
    ushort_t* pong = xab;
    for (int i = 0; i < LAYERS; i++) {
        float beta = logf(0.5f / (float)(i + 1) + 1.0f);
        layer_fused<<<M_PAD / 64, 256, 0, stream>>>(
            row_start, perm, ping, h0b, WtL + (size_t)i * HDIM * HDIM, pong, beta);
        if (i == 0) { ping = xab; pong = xbb; }
        else { ushort_t* tmp = ping; ping = pong; pong = tmp; }
    }
    // L0->xab, L1->xbb, ..., L7->xbb; ping == xbb here
    fc1_mfma<<<M_PAD / 64, 256, 0, stream>>>(ping, Wt1, b1, out);
}